// Round 7
// baseline (207.897 us; speedup 1.0000x reference)
//
#include <hip/hip_runtime.h>

// TermME round 6 (resubmit; round 6 hit GPUAcquisitionTimeout, never ran):
// collapse to a 25,200-state coefficient table.
// result_i = pc_i * (prem_i * A(s) - sa_i * B(s) - C(s)),  s = (dm0, age, term)
//   A = sum_t D_t dv_t  (minus commission dv_0 term when dm0==0)
//   B = sum_t D_t q_t dv_t
//   C = sum_t D_t e_t dv_t (+300 acq when dm0==0), e_t = 5*1.01^(t/12)
// D_t depends only on the discrete state -> precompute (A,B,C) once
// (kernel 1, direct monthly port of the reference recurrence), then the
// 2M-policy pass (kernel 2) is a pure streaming read + float4 L2 gather.

#define NSTATE (3 * 240 * 35)   // term_idx x dm0 x (age-20) = 25200

__global__ __launch_bounds__(256) void build_table_kernel(
    const float* __restrict__ mort_table,    // 100 x 6
    const float* __restrict__ disc_rate_ann, // 30
    float4* __restrict__ tbl)
{
    __shared__ float s_mortm[600];
    __shared__ float s_dv[240];
    __shared__ float s_lmm[8];

    const int tid = threadIdx.x;
    const float tw = 1.0f / 12.0f;
    const float c  = powf(1.01f, tw);

    for (int j = tid; j < 600; j += 256)
        s_mortm[j] = 1.0f - powf(1.0f - mort_table[j], tw);
    for (int j = tid; j < 240; j += 256)
        s_dv[j] = powf(1.0f + disc_rate_ann[j / 12 + 1], -(float)j * tw);
    if (tid < 8) {
        float lr = fmaxf(0.1f - 0.02f * (float)min(tid, 4), 0.02f);
        s_lmm[tid] = powf(1.0f - lr, tw);
    }
    __syncthreads();

    const int g = blockIdx.x * 256 + tid;
    if (g >= NSTATE) return;

    const int ti   = g / (240 * 35);
    const int r    = g - ti * (240 * 35);
    const int dm0  = r / 35;
    const int age  = 20 + (r - dm0 * 35);
    const int term = 10 + 5 * ti;
    const int rem  = term * 12 - dm0;        // months until maturity

    float A = 0.0f, B = 0.0f, C = 0.0f;
    if (rem > 0) {
        float D = 1.0f, ep = 5.0f;
        if (dm0 == 0) { A -= 1.0f; C += 300.0f; }   // commission + acq at t=0
        for (int t = 0; t < rem; ++t) {
            int   dur = (dm0 + t) / 12;
            int   dc  = min(dur, 5);
            float q   = s_mortm[(age - 18 + dur - dc) * 6 + dc];
            float dv  = s_dv[t];
            A = fmaf(D, dv, A);
            B = fmaf(D * q, dv, B);
            C = fmaf(D * ep, dv, C);
            D *= (1.0f - q) * s_lmm[min(dur, 4)];
            ep *= c;
        }
    }
    tbl[g] = make_float4(A, B, C, 0.0f);
}

__global__ __launch_bounds__(256) void policy_sum_kernel(
    const float* __restrict__ premium_pp,
    const float* __restrict__ sum_assured,
    const float* __restrict__ policy_count,
    const int*   __restrict__ duration_mth,
    const int*   __restrict__ age_at_entry,
    const int*   __restrict__ policy_term,
    const float4* __restrict__ tbl,
    float* __restrict__ out,
    int n)
{
    __shared__ float s_red[4];
    const int tid = threadIdx.x;
    const int i   = blockIdx.x * 256 + tid;

    float v = 0.0f;
    if (i < n) {
        int ti  = (policy_term[i] - 10) / 5;            // 0,1,2
        int idx = (ti * 240 + duration_mth[i]) * 35 + (age_at_entry[i] - 20);
        float4 t4 = tbl[idx];                           // L2-resident gather
        v = policy_count[i] *
            (premium_pp[i] * t4.x - sum_assured[i] * t4.y - t4.z);
    }
    for (int off = 32; off > 0; off >>= 1)
        v += __shfl_down(v, off, 64);
    if ((tid & 63) == 0) s_red[tid >> 6] = v;
    __syncthreads();
    if (tid == 0)
        atomicAdd(out, s_red[0] + s_red[1] + s_red[2] + s_red[3]);
}

extern "C" void kernel_launch(void* const* d_in, const int* in_sizes, int n_in,
                              void* d_out, int out_size, void* d_ws, size_t ws_size,
                              hipStream_t stream) {
    const float* premium_pp    = (const float*)d_in[0];
    const float* sum_assured   = (const float*)d_in[1];
    const float* policy_count  = (const float*)d_in[2];
    const float* mort_table    = (const float*)d_in[3];
    const float* disc_rate_ann = (const float*)d_in[4];
    const int*   duration_mth  = (const int*)d_in[5];
    const int*   age_at_entry  = (const int*)d_in[6];
    const int*   policy_term   = (const int*)d_in[7];
    const int n = in_sizes[0];

    float4* tbl = (float4*)d_ws;   // 25200 * 16 B = 403 KB scratch

    hipMemsetAsync(d_out, 0, sizeof(float), stream);
    build_table_kernel<<<(NSTATE + 255) / 256, 256, 0, stream>>>(
        mort_table, disc_rate_ann, tbl);
    policy_sum_kernel<<<(n + 255) / 256, 256, 0, stream>>>(
        premium_pp, sum_assured, policy_count,
        duration_mth, age_at_entry, policy_term, tbl, (float*)d_out, n);
}

// Round 8
// 124.128 us; speedup vs baseline: 1.6749x; 1.6749x over previous
//
#include <hip/hip_runtime.h>

// TermME round 8: same 25,200-state linearization as R6/R7
//   result_i = pc_i * (prem_i*A(s) - sa_i*B(s) - C(s)), s=(dm0,age,term)
// R7 post-mortem: policy_sum was latency-serialized (VGPR=8, 1 policy/thread,
// 5 dependent memory round-trips) + 7813 same-address atomics.
// Fix: 4 policies/thread via int4/float4 coalesced loads (10 independent
// loads in flight), per-block partials to d_ws, separate reduce kernel
// (no global atomics at all).

#define NSTATE (3 * 240 * 35)   // term_idx x dm0 x (age-20) = 25200
#define BLOCK 256
#define PPT 4                   // policies per thread

__global__ __launch_bounds__(256) void build_table_kernel(
    const float* __restrict__ mort_table,    // 100 x 6
    const float* __restrict__ disc_rate_ann, // 30
    float4* __restrict__ tbl)
{
    __shared__ float s_mortm[600];
    __shared__ float s_dv[240];
    __shared__ float s_lmm[8];

    const int tid = threadIdx.x;
    const float tw = 1.0f / 12.0f;
    const float c  = powf(1.01f, tw);

    for (int j = tid; j < 600; j += 256)
        s_mortm[j] = 1.0f - powf(1.0f - mort_table[j], tw);
    for (int j = tid; j < 240; j += 256)
        s_dv[j] = powf(1.0f + disc_rate_ann[j / 12 + 1], -(float)j * tw);
    if (tid < 8) {
        float lr = fmaxf(0.1f - 0.02f * (float)min(tid, 4), 0.02f);
        s_lmm[tid] = powf(1.0f - lr, tw);
    }
    __syncthreads();

    const int g = blockIdx.x * 256 + tid;
    if (g >= NSTATE) return;

    const int ti   = g / (240 * 35);
    const int r    = g - ti * (240 * 35);
    const int dm0  = r / 35;
    const int age  = 20 + (r - dm0 * 35);
    const int term = 10 + 5 * ti;
    const int rem  = term * 12 - dm0;        // months until maturity

    float A = 0.0f, B = 0.0f, C = 0.0f;
    if (rem > 0) {
        float D = 1.0f, ep = 5.0f;
        if (dm0 == 0) { A -= 1.0f; C += 300.0f; }   // commission + acq at t=0
        for (int t = 0; t < rem; ++t) {
            int   dur = (dm0 + t) / 12;
            int   dc  = min(dur, 5);
            float q   = s_mortm[(age - 18 + dur - dc) * 6 + dc];
            float dv  = s_dv[t];
            A = fmaf(D, dv, A);
            B = fmaf(D * q, dv, B);
            C = fmaf(D * ep, dv, C);
            D *= (1.0f - q) * s_lmm[min(dur, 4)];
            ep *= c;
        }
    }
    tbl[g] = make_float4(A, B, C, 0.0f);
}

__device__ __forceinline__ float eval_one(
    float prem, float sa, float pc, int dm0, int age, int term,
    const float4* __restrict__ tbl)
{
    int ti  = (term - 10) / 5;                       // 0,1,2
    int idx = (ti * 240 + dm0) * 35 + (age - 20);
    float4 t4 = tbl[idx];                            // L2-resident gather
    return pc * (prem * t4.x - sa * t4.y - t4.z);
}

__global__ __launch_bounds__(BLOCK) void policy_sum_kernel(
    const float* __restrict__ premium_pp,
    const float* __restrict__ sum_assured,
    const float* __restrict__ policy_count,
    const int*   __restrict__ duration_mth,
    const int*   __restrict__ age_at_entry,
    const int*   __restrict__ policy_term,
    const float4* __restrict__ tbl,
    float* __restrict__ partials,
    int n)
{
    __shared__ float s_red[BLOCK / 64];
    const int tid = threadIdx.x;
    const int g4  = blockIdx.x * BLOCK + tid;        // group of 4 policies
    const int b   = g4 * PPT;

    float acc = 0.0f;
    if (b + PPT <= n) {
        // vector path: 6 coalesced 16-B loads + 4 independent gathers
        int4   dm = *(const int4*)  (duration_mth + b);
        int4   ag = *(const int4*)  (age_at_entry + b);
        int4   tm = *(const int4*)  (policy_term  + b);
        float4 pr = *(const float4*)(premium_pp   + b);
        float4 sa = *(const float4*)(sum_assured  + b);
        float4 pc = *(const float4*)(policy_count + b);
        acc += eval_one(pr.x, sa.x, pc.x, dm.x, ag.x, tm.x, tbl);
        acc += eval_one(pr.y, sa.y, pc.y, dm.y, ag.y, tm.y, tbl);
        acc += eval_one(pr.z, sa.z, pc.z, dm.z, ag.z, tm.z, tbl);
        acc += eval_one(pr.w, sa.w, pc.w, dm.w, ag.w, tm.w, tbl);
    } else {
        for (int i = b; i < n; ++i)
            acc += eval_one(premium_pp[i], sum_assured[i], policy_count[i],
                            duration_mth[i], age_at_entry[i], policy_term[i], tbl);
    }

    for (int off = 32; off > 0; off >>= 1)
        acc += __shfl_down(acc, off, 64);
    if ((tid & 63) == 0) s_red[tid >> 6] = acc;
    __syncthreads();
    if (tid == 0) {
        float bsum = 0.0f;
        #pragma unroll
        for (int w = 0; w < BLOCK / 64; ++w) bsum += s_red[w];
        partials[blockIdx.x] = bsum;
    }
}

__global__ __launch_bounds__(256) void reduce_kernel(
    const float* __restrict__ partials, int nb, float* __restrict__ out)
{
    __shared__ double s_red[4];
    double s = 0.0;
    for (int j = threadIdx.x; j < nb; j += 256) s += (double)partials[j];
    for (int off = 32; off > 0; off >>= 1)
        s += __shfl_down(s, off, 64);
    if ((threadIdx.x & 63) == 0) s_red[threadIdx.x >> 6] = s;
    __syncthreads();
    if (threadIdx.x == 0)
        out[0] = (float)(s_red[0] + s_red[1] + s_red[2] + s_red[3]);
}

extern "C" void kernel_launch(void* const* d_in, const int* in_sizes, int n_in,
                              void* d_out, int out_size, void* d_ws, size_t ws_size,
                              hipStream_t stream) {
    const float* premium_pp    = (const float*)d_in[0];
    const float* sum_assured   = (const float*)d_in[1];
    const float* policy_count  = (const float*)d_in[2];
    const float* mort_table    = (const float*)d_in[3];
    const float* disc_rate_ann = (const float*)d_in[4];
    const int*   duration_mth  = (const int*)d_in[5];
    const int*   age_at_entry  = (const int*)d_in[6];
    const int*   policy_term   = (const int*)d_in[7];
    const int n = in_sizes[0];

    float4* tbl      = (float4*)d_ws;                 // 25200*16 B = 403 KB
    float*  partials = (float*)((char*)d_ws + NSTATE * sizeof(float4));

    const int nblocks = (n + BLOCK * PPT - 1) / (BLOCK * PPT);  // ~1954

    build_table_kernel<<<(NSTATE + 255) / 256, 256, 0, stream>>>(
        mort_table, disc_rate_ann, tbl);
    policy_sum_kernel<<<nblocks, BLOCK, 0, stream>>>(
        premium_pp, sum_assured, policy_count,
        duration_mth, age_at_entry, policy_term, tbl, partials, n);
    reduce_kernel<<<1, 256, 0, stream>>>(partials, nblocks, (float*)d_out);
}

// Round 9
// 108.219 us; speedup vs baseline: 1.9211x; 1.1470x over previous
//
#include <hip/hip_runtime.h>

// TermME round 9: 25,200-state linearization (as R8), with:
//  - build_table: policy-year Horner chunks (R4-validated math) -> serial
//    critical path ~20 iters instead of 240 monthly iters
//  - policy_sum: 8 policies/thread, 12 streaming float4/int4 loads + 8
//    independent table gathers in flight; 977 blocks
//  - no global atomics, no d_out memset (reduce writes out[0] directly)

#define NSTATE (3 * 240 * 35)   // term_idx x dm0 x (age-20) = 25200
#define BLOCK 256
#define PPT 8                   // policies per thread

__global__ __launch_bounds__(256) void build_table_kernel(
    const float* __restrict__ mort_table,    // 100 x 6
    const float* __restrict__ disc_rate_ann, // 30
    float4* __restrict__ tbl)
{
    __shared__ float s_mortm[600];
    __shared__ float s_dv[240];
    __shared__ float s_lmm[8];
    __shared__ float s_cp[13];

    const int tid = threadIdx.x;
    const float tw = 1.0f / 12.0f;
    const float c  = powf(1.01f, tw);

    for (int j = tid; j < 600; j += 256)
        s_mortm[j] = 1.0f - powf(1.0f - mort_table[j], tw);
    for (int j = tid; j < 240; j += 256)
        s_dv[j] = powf(1.0f + disc_rate_ann[j / 12 + 1], -(float)j * tw);
    if (tid < 8) {
        float lr = fmaxf(0.1f - 0.02f * (float)min(tid, 4), 0.02f);
        s_lmm[tid] = powf(1.0f - lr, tw);
    }
    if (tid < 13) s_cp[tid] = 5.0f * powf(1.01f, (float)tid * tw);
    __syncthreads();

    const int g = blockIdx.x * 256 + tid;
    if (g >= NSTATE) return;

    const int ti   = g / (240 * 35);
    const int r    = g - ti * (240 * 35);
    const int dm0  = r / 35;
    const int age  = 20 + (r - dm0 * 35);
    const int term = 10 + 5 * ti;

    const int d0     = dm0 / 12;
    const int ph     = dm0 - d0 * 12;
    const int p      = ph ? (12 - ph) : 0;
    const int dfirst = d0 + (ph ? 1 : 0);
    const int Y      = term - dfirst;       // full-year chunks (>=0)

    float A = 0.0f, B = 0.0f, C = 0.0f, D = 1.0f;
    if (dm0 == 0) { A -= 1.0f; C += 300.0f; }   // commission + acq at t=0

    // partial chunk: months 0..p-1 at dur=d0
    if (p > 0) {
        int   dc = min(d0, 5);
        float q  = s_mortm[(age - 18 + d0 - dc) * 6 + dc];
        float k1 = (1.0f - q) * s_lmm[min(d0, 4)];
        float ep = 5.0f;
        for (int m = 0; m < p; ++m) {
            float dv = s_dv[m];
            A = fmaf(D, dv, A);
            B = fmaf(D * q, dv, B);
            C = fmaf(D * ep, dv, C);
            D *= k1;
            ep *= c;
        }
    }

    // full policy-year chunks
    float e = s_cp[p];
    for (int y = 0; y < Y; ++y) {
        int   d  = dfirst + y;
        int   dc = min(d, 5);
        float q  = s_mortm[(age - 18 + d - dc) * 6 + dc];
        float k1 = (1.0f - q) * s_lmm[min(d, 4)];
        float kc = k1 * c;
        const float* bp = &s_dv[p + 12 * y];
        float a0 = bp[0],  a1 = bp[1],  a2 = bp[2],  a3 = bp[3];
        float a4 = bp[4],  a5 = bp[5],  a6 = bp[6],  a7 = bp[7];
        float a8 = bp[8],  a9 = bp[9],  a10 = bp[10], a11 = bp[11];
        float S1 = a11, S2 = a11;
        S1 = fmaf(k1, S1, a10); S2 = fmaf(kc, S2, a10);
        S1 = fmaf(k1, S1, a9);  S2 = fmaf(kc, S2, a9);
        S1 = fmaf(k1, S1, a8);  S2 = fmaf(kc, S2, a8);
        S1 = fmaf(k1, S1, a7);  S2 = fmaf(kc, S2, a7);
        S1 = fmaf(k1, S1, a6);  S2 = fmaf(kc, S2, a6);
        S1 = fmaf(k1, S1, a5);  S2 = fmaf(kc, S2, a5);
        S1 = fmaf(k1, S1, a4);  S2 = fmaf(kc, S2, a4);
        S1 = fmaf(k1, S1, a3);  S2 = fmaf(kc, S2, a3);
        S1 = fmaf(k1, S1, a2);  S2 = fmaf(kc, S2, a2);
        S1 = fmaf(k1, S1, a1);  S2 = fmaf(kc, S2, a1);
        S1 = fmaf(k1, S1, a0);  S2 = fmaf(kc, S2, a0);
        A = fmaf(D, S1, A);
        B = fmaf(D * q, S1, B);
        C = fmaf(D * e, S2, C);
        float k2 = k1 * k1, k4 = k2 * k2, k8 = k4 * k4;
        D *= k8 * k4;                        // k1^12
        e *= 1.01f;
    }
    tbl[g] = make_float4(A, B, C, 0.0f);
}

__device__ __forceinline__ float eval_one(
    float prem, float sa, float pc, int dm0, int age, int term,
    const float4* __restrict__ tbl)
{
    int ti  = (term - 10) / 5;                       // 0,1,2
    int idx = (ti * 240 + dm0) * 35 + (age - 20);
    float4 t4 = tbl[idx];                            // L2-resident gather
    return pc * (prem * t4.x - sa * t4.y - t4.z);
}

__global__ __launch_bounds__(BLOCK) void policy_sum_kernel(
    const float* __restrict__ premium_pp,
    const float* __restrict__ sum_assured,
    const float* __restrict__ policy_count,
    const int*   __restrict__ duration_mth,
    const int*   __restrict__ age_at_entry,
    const int*   __restrict__ policy_term,
    const float4* __restrict__ tbl,
    float* __restrict__ partials,
    int n)
{
    __shared__ float s_red[BLOCK / 64];
    const int tid = threadIdx.x;
    const int b   = (blockIdx.x * BLOCK + tid) * PPT;

    float acc = 0.0f;
    if (b + PPT <= n) {
        int4   dm0 = *(const int4*)  (duration_mth + b);
        int4   dm1 = *(const int4*)  (duration_mth + b + 4);
        int4   ag0 = *(const int4*)  (age_at_entry + b);
        int4   ag1 = *(const int4*)  (age_at_entry + b + 4);
        int4   tm0 = *(const int4*)  (policy_term  + b);
        int4   tm1 = *(const int4*)  (policy_term  + b + 4);
        float4 pr0 = *(const float4*)(premium_pp   + b);
        float4 pr1 = *(const float4*)(premium_pp   + b + 4);
        float4 sa0 = *(const float4*)(sum_assured  + b);
        float4 sa1 = *(const float4*)(sum_assured  + b + 4);
        float4 pc0 = *(const float4*)(policy_count + b);
        float4 pc1 = *(const float4*)(policy_count + b + 4);
        acc += eval_one(pr0.x, sa0.x, pc0.x, dm0.x, ag0.x, tm0.x, tbl);
        acc += eval_one(pr0.y, sa0.y, pc0.y, dm0.y, ag0.y, tm0.y, tbl);
        acc += eval_one(pr0.z, sa0.z, pc0.z, dm0.z, ag0.z, tm0.z, tbl);
        acc += eval_one(pr0.w, sa0.w, pc0.w, dm0.w, ag0.w, tm0.w, tbl);
        acc += eval_one(pr1.x, sa1.x, pc1.x, dm1.x, ag1.x, tm1.x, tbl);
        acc += eval_one(pr1.y, sa1.y, pc1.y, dm1.y, ag1.y, tm1.y, tbl);
        acc += eval_one(pr1.z, sa1.z, pc1.z, dm1.z, ag1.z, tm1.z, tbl);
        acc += eval_one(pr1.w, sa1.w, pc1.w, dm1.w, ag1.w, tm1.w, tbl);
    } else {
        for (int i = b; i < n; ++i)
            acc += eval_one(premium_pp[i], sum_assured[i], policy_count[i],
                            duration_mth[i], age_at_entry[i], policy_term[i], tbl);
    }

    for (int off = 32; off > 0; off >>= 1)
        acc += __shfl_down(acc, off, 64);
    if ((tid & 63) == 0) s_red[tid >> 6] = acc;
    __syncthreads();
    if (tid == 0) {
        float bsum = 0.0f;
        #pragma unroll
        for (int w = 0; w < BLOCK / 64; ++w) bsum += s_red[w];
        partials[blockIdx.x] = bsum;
    }
}

__global__ __launch_bounds__(256) void reduce_kernel(
    const float* __restrict__ partials, int nb, float* __restrict__ out)
{
    __shared__ double s_red[4];
    double s = 0.0;
    for (int j = threadIdx.x; j < nb; j += 256) s += (double)partials[j];
    for (int off = 32; off > 0; off >>= 1)
        s += __shfl_down(s, off, 64);
    if ((threadIdx.x & 63) == 0) s_red[threadIdx.x >> 6] = s;
    __syncthreads();
    if (threadIdx.x == 0)
        out[0] = (float)(s_red[0] + s_red[1] + s_red[2] + s_red[3]);
}

extern "C" void kernel_launch(void* const* d_in, const int* in_sizes, int n_in,
                              void* d_out, int out_size, void* d_ws, size_t ws_size,
                              hipStream_t stream) {
    const float* premium_pp    = (const float*)d_in[0];
    const float* sum_assured   = (const float*)d_in[1];
    const float* policy_count  = (const float*)d_in[2];
    const float* mort_table    = (const float*)d_in[3];
    const float* disc_rate_ann = (const float*)d_in[4];
    const int*   duration_mth  = (const int*)d_in[5];
    const int*   age_at_entry  = (const int*)d_in[6];
    const int*   policy_term   = (const int*)d_in[7];
    const int n = in_sizes[0];

    float4* tbl      = (float4*)d_ws;                 // 25200*16 B = 403 KB
    float*  partials = (float*)((char*)d_ws + NSTATE * sizeof(float4));

    const int nblocks = (n + BLOCK * PPT - 1) / (BLOCK * PPT);  // ~977

    build_table_kernel<<<(NSTATE + 255) / 256, 256, 0, stream>>>(
        mort_table, disc_rate_ann, tbl);
    policy_sum_kernel<<<nblocks, BLOCK, 0, stream>>>(
        premium_pp, sum_assured, policy_count,
        duration_mth, age_at_entry, policy_term, tbl, partials, n);
    reduce_kernel<<<1, 256, 0, stream>>>(partials, nblocks, (float*)d_out);
}